// Round 15
// baseline (923.172 us; speedup 1.0000x reference)
//
#include <hip/hip_runtime.h>

#define LTOT 2048
#define BATCH 2
#define NTOK 4096
#define DMODEL 2048
#define DSTATE 128
#define NH 64
#define HD 64
#define DINNER 4096
#define CONVD 4352
#define XDTC 4416
#define INP 8512
#define INTER_ 5632
#define CHUNK_ 128
#define NCH 16
#define EPSF 1e-6f

typedef __bf16 bf16x8 __attribute__((ext_vector_type(8)));
typedef float f32x4 __attribute__((ext_vector_type(4)));
typedef unsigned short u16x4 __attribute__((ext_vector_type(4)));
typedef unsigned short u16x8 __attribute__((ext_vector_type(8)));

__device__ __forceinline__ unsigned short f2b(float f){
  unsigned int u = __builtin_bit_cast(unsigned int, f);
  u += 0x7fffu + ((u >> 16) & 1u);
  return (unsigned short)(u >> 16);
}
__device__ __forceinline__ float b2f(unsigned short h){
  return __builtin_bit_cast(float, ((unsigned int)h) << 16);
}
__device__ __forceinline__ f32x4 mfma16(bf16x8 a, bf16x8 b, f32x4 c){
  return __builtin_amdgcn_mfma_f32_16x16x32_bf16(a, b, c, 0, 0, 0);
}
// async global->LDS, 16B per lane, wave-uniform LDS base + lane*16
typedef const __attribute__((address_space(1))) void* gas_t;
typedef __attribute__((address_space(3))) void* las_t;
__device__ __forceinline__ void gload16(const void* g, void* l){
  __builtin_amdgcn_global_load_lds((gas_t)g, (las_t)l, 16, 0, 0);
}

// ---------------- weight convert: fp32 W[K][N] -> bf16 WT[(n*rstride+roff)][K] ----------------
__global__ __launch_bounds__(256) void wconv_kernel(const float* __restrict__ W,
                                                    unsigned short* __restrict__ WT,
                                                    int K, int N, int rstride, int roff)
{
  __shared__ unsigned short t[64][72];
  int n0 = blockIdx.x * 64, k0 = blockIdx.y * 64;
  int tid = threadIdx.x;
  int kl = tid >> 4, nl4 = (tid & 15) * 4;
  #pragma unroll
  for (int it = 0; it < 4; it++){
    int kk = kl + it * 16;
    float4 v = make_float4(0.f, 0.f, 0.f, 0.f);
    if (n0 < N) v = *(const float4*)&W[(size_t)(k0 + kk) * N + n0 + nl4];
    t[nl4 + 0][kk] = f2b(v.x);
    t[nl4 + 1][kk] = f2b(v.y);
    t[nl4 + 2][kk] = f2b(v.z);
    t[nl4 + 3][kk] = f2b(v.w);
  }
  __syncthreads();
  int nr = tid >> 3, k8 = (tid & 7) * 8;
  #pragma unroll
  for (int it = 0; it < 2; it++){
    int nn = nr + it * 32;
    *(u16x8*)&WT[((size_t)(n0 + nn) * rstride + roff) * K + k0 + k8] = *(const u16x8*)&t[nn][k8];
  }
}

// ---------------- RMSNorm: fp32 in -> bf16 out ----------------
__global__ __launch_bounds__(256) void rms_kernel(const float* __restrict__ x,
                                                  const float* __restrict__ w,
                                                  unsigned short* __restrict__ out, int width)
{
  int row = blockIdx.x, tid = threadIdx.x;
  const float* xr = x + (size_t)row * width;
  unsigned short* orow = out + (size_t)row * width;
  int nv = width >> 2;
  float ss = 0.f;
  for (int i = tid; i < nv; i += 256){
    float4 v = ((const float4*)xr)[i];
    ss += v.x*v.x + v.y*v.y + v.z*v.z + v.w*v.w;
  }
  #pragma unroll
  for (int off = 32; off > 0; off >>= 1) ss += __shfl_down(ss, off, 64);
  __shared__ float red[4];
  if ((tid & 63) == 0) red[tid >> 6] = ss;
  __syncthreads();
  float tot = red[0] + red[1] + red[2] + red[3];
  float scale = rsqrtf(tot / (float)width + EPSF);
  for (int i = tid; i < nv; i += 256){
    float4 v = ((const float4*)xr)[i];
    float4 wv = ((const float4*)w)[i];
    u16x4 o = { f2b(v.x * scale * wv.x), f2b(v.y * scale * wv.y),
                f2b(v.z * scale * wv.z), f2b(v.w * scale * wv.w) };
    ((u16x4*)orow)[i] = o;
  }
}

// ---------------- Gated RMSNorm: y bf16, z bf16 -> out bf16 ----------------
__global__ __launch_bounds__(256) void rms_gated_kernel(const unsigned short* __restrict__ y,
                                                        const unsigned short* __restrict__ z,
                                                        const float* __restrict__ w,
                                                        unsigned short* __restrict__ out)
{
  int row = blockIdx.x, tid = threadIdx.x;
  const unsigned short* yr = y + (size_t)row * DINNER;
  const unsigned short* zr = z + (size_t)row * DINNER;
  unsigned short* orow = out + (size_t)row * DINNER;
  float g[16];
  float ss = 0.f;
  #pragma unroll
  for (int ii = 0; ii < 4; ii++){
    int i = tid + ii * 256;
    u16x4 yv = ((const u16x4*)yr)[i];
    u16x4 zv = ((const u16x4*)zr)[i];
    #pragma unroll
    for (int e = 0; e < 4; e++){
      float zf = b2f(zv[e]);
      float yf = b2f(yv[e]);
      float gg = yf * (zf / (1.f + expf(-zf)));
      g[ii * 4 + e] = gg;
      ss += gg * gg;
    }
  }
  #pragma unroll
  for (int off = 32; off > 0; off >>= 1) ss += __shfl_down(ss, off, 64);
  __shared__ float red[4];
  if ((tid & 63) == 0) red[tid >> 6] = ss;
  __syncthreads();
  float tot = red[0] + red[1] + red[2] + red[3];
  float scale = rsqrtf(tot / (float)DINNER + EPSF);
  #pragma unroll
  for (int ii = 0; ii < 4; ii++){
    int i = tid + ii * 256;
    float4 wv = ((const float4*)w)[i];
    u16x4 o;
    #pragma unroll
    for (int e = 0; e < 4; e++) o[e] = f2b(g[ii * 4 + e] * scale * (&wv.x)[e]);
    ((u16x4*)orow)[i] = o;
  }
}

// ---------------- GEMM3: 128(M)x256(N), BK=32, 8 waves, 3x24KB bufs -> 2 blocks/CU -------------
// Grouped raster GM=8; glu=1: interleaved gate/up GLU epilogue (R13-verified). Staging uses
// hoisted running base pointers (no per-tile 64-bit muls).
__global__ __launch_bounds__(512, 2) void gemm3_kernel(const unsigned short* __restrict__ A,
                                                       const unsigned short* __restrict__ BT,
                                                       const float* __restrict__ addsrc,
                                                       float* __restrict__ Cf,
                                                       unsigned short* __restrict__ Cb,
                                                       unsigned short* __restrict__ Cb2, int splitN,
                                                       int glu,
                                                       float* __restrict__ dtraw,
                                                       int M, int N, int K)
{
  extern __shared__ unsigned short lds[];
  int tid = threadIdx.x, lane = tid & 63, w = tid >> 6;
  int wm = w >> 2, wn = w & 3;
  int bid = blockIdx.x + blockIdx.y * gridDim.x;
  int nwg = gridDim.x * gridDim.y;
  int q8 = nwg >> 3, r8 = nwg & 7;
  int xcd = bid & 7, boff = bid >> 3;
  int wgid = (xcd < r8 ? xcd * (q8 + 1) : r8 * (q8 + 1) + (xcd - r8) * q8) + boff;
  int gsz = 8 * gridDim.x;
  int grp = wgid / gsz, rem = wgid % gsz;
  int bm = (grp * 8 + (rem & 7)) * 128;
  int bn = (rem >> 3) * 256;

  int gsrc = (((lane & 3) ^ ((lane >> 2) & 3) ^ ((4 * w + (lane >> 4)) & 3)) << 3);
  int prow_l = lane >> 2;
  int ko = (((lane >> 4) ^ (lane & 3) ^ ((lane >> 2) & 3)) << 3);
  int rsel = (lane & 15) * 32 + ko;

  // hoisted staging bases (advance by kt*32 via shift+add only)
  const unsigned short* pA  = A  + (size_t)(bm +       w * 16 + prow_l) * K + gsrc;
  const unsigned short* pB0 = BT + (size_t)(bn +       w * 16 + prow_l) * K + gsrc;
  const unsigned short* pB1 = BT + (size_t)(bn + 128 + w * 16 + prow_l) * K + gsrc;

  f32x4 acc[4][4] = {};
  int NT = K >> 5;

  #define STAGE(kt, bsel)                                                              \
    {                                                                                  \
      unsigned short* bb_ = &lds[(bsel) * 12288];                                      \
      size_t kof_ = (size_t)(kt) << 5;                                                 \
      gload16(pA  + kof_, &bb_[w * 512]);                                              \
      gload16(pB0 + kof_, &bb_[4096 + w * 512]);                                       \
      gload16(pB1 + kof_, &bb_[8192 + w * 512]);                                       \
    }

  STAGE(0, 0)
  STAGE(1, 1)
  asm volatile("s_waitcnt vmcnt(3)" ::: "memory");
  __builtin_amdgcn_s_barrier();
  asm volatile("" ::: "memory");

  for (int t = 0; t < NT; ++t){
    const unsigned short* bufc = &lds[(t % 3) * 12288];
    bf16x8 afr[4], bfr[4];
    #pragma unroll
    for (int i = 0; i < 4; ++i)
      afr[i] = *(const bf16x8*)&bufc[(wm * 64 + i * 16) * 32 + rsel];
    #pragma unroll
    for (int c = 0; c < 4; ++c)
      bfr[c] = *(const bf16x8*)&bufc[4096 + (wn * 64 + c * 16) * 32 + rsel];
    if (t + 2 < NT) STAGE(t + 2, (t + 2) % 3)
    __builtin_amdgcn_s_setprio(1);
    #pragma unroll
    for (int i = 0; i < 4; ++i)
      #pragma unroll
      for (int c = 0; c < 4; ++c)
        acc[i][c] = mfma16(afr[i], bfr[c], acc[i][c]);
    __builtin_amdgcn_s_setprio(0);
    if (t + 2 < NT)      asm volatile("s_waitcnt vmcnt(3)" ::: "memory");
    else if (t + 1 < NT) asm volatile("s_waitcnt vmcnt(0)" ::: "memory");
    asm volatile("" ::: "memory");
    __builtin_amdgcn_s_barrier();
    asm volatile("" ::: "memory");
  }
  #undef STAGE

  int r0 = bm + wm * 64 + ((lane >> 4) << 2);
  int c0 = bn + wn * 64 + (lane & 15);
  #pragma unroll
  for (int i = 0; i < 4; ++i){
    #pragma unroll
    for (int j = 0; j < 4; ++j){
      int cc = c0 + j * 16;
      if (glu){
        #pragma unroll
        for (int e = 0; e < 4; ++e){
          float v = acc[i][j][e];
          float pv = __shfl_xor(v, 1, 64);
          if (!(lane & 1)){
            int rr = r0 + i * 16 + e;
            float res = v / (1.f + expf(-v)) * pv;   // silu(gate)*up
            Cb[(size_t)rr * (N >> 1) + (cc >> 1)] = f2b(res);
          }
        }
      } else if (cc < N){
        #pragma unroll
        for (int e = 0; e < 4; ++e){
          int rr = r0 + i * 16 + e;
          float v = acc[i][j][e];
          if (Cf){
            size_t idx = (size_t)rr * N + cc;
            if (addsrc) v += addsrc[idx];
            Cf[idx] = v;
          } else if (cc < splitN){
            Cb[(size_t)rr * splitN + cc] = f2b(v);
          } else {
            Cb2[(size_t)rr * (N - splitN) + (cc - splitN)] = f2b(v);
            if (dtraw && cc >= N - NH) dtraw[(size_t)rr * NH + (cc - (N - NH))] = v;
          }
        }
      }
    }
  }
}

// ---------------- GEMM4: 128x128, BK=32, 4 waves, 3x16KB bufs -> 3 blocks/CU ------------------
// Runtime GM raster parameter; full split epilogue (zbuf/xdt/dtraw) ported from gemm3 so
// narrow-tile grids (94% round-fill for in_proj) can serve every GEMM shape.
__global__ __launch_bounds__(256, 3) void gemm4_kernel(const unsigned short* __restrict__ A,
                                                       const unsigned short* __restrict__ BT,
                                                       const float* __restrict__ addsrc,
                                                       float* __restrict__ Cf,
                                                       unsigned short* __restrict__ Cb,
                                                       unsigned short* __restrict__ Cb2, int splitN,
                                                       float* __restrict__ dtraw,
                                                       int M, int N, int K, int GM)
{
  extern __shared__ unsigned short lds[];
  int tid = threadIdx.x, lane = tid & 63, w = tid >> 6;
  int wm = w >> 1, wn = w & 1;
  int bid = blockIdx.x + blockIdx.y * gridDim.x;
  int nwg = gridDim.x * gridDim.y;
  int q8 = nwg >> 3, r8 = nwg & 7;
  int xcd = bid & 7, boff = bid >> 3;
  int wgid = (xcd < r8 ? xcd * (q8 + 1) : r8 * (q8 + 1) + (xcd - r8) * q8) + boff;
  int gsz = GM * gridDim.x;
  int grp = wgid / gsz, rem = wgid % gsz;
  int bm = (grp * GM + (rem % GM)) * 128;
  int bn = (rem / GM) * 128;

  int gsrc = (((lane & 3) ^ ((lane >> 2) & 3) ^ ((4 * w + (lane >> 4)) & 3)) << 3);
  int prow_l = lane >> 2;
  int ko = (((lane >> 4) ^ (lane & 3) ^ ((lane >> 2) & 3)) << 3);
  int rsel = (lane & 15) * 32 + ko;

  const unsigned short* pA0 = A  + (size_t)(bm +      w * 16 + prow_l) * K + gsrc;
  const unsigned short* pA1 = A  + (size_t)(bm + 64 + w * 16 + prow_l) * K + gsrc;
  const unsigned short* pB0 = BT + (size_t)(bn +      w * 16 + prow_l) * K + gsrc;
  const unsigned short* pB1 = BT + (size_t)(bn + 64 + w * 16 + prow_l) * K + gsrc;

  f32x4 acc[4][4] = {};
  int NT = K >> 5;

  #define STAGE4(kt, bsel)                                                             \
    {                                                                                  \
      unsigned short* bb_ = &lds[(bsel) * 8192];                                       \
      size_t kof_ = (size_t)(kt) << 5;                                                 \
      gload16(pA0 + kof_, &bb_[w * 512]);                                              \
      gload16(pA1 + kof_, &bb_[2048 + w * 512]);                                       \
      gload16(pB0 + kof_, &bb_[4096 + w * 512]);                                       \
      gload16(pB1 + kof_, &bb_[6144 + w * 512]);                                       \
    }

  STAGE4(0, 0)
  STAGE4(1, 1)
  asm volatile("s_waitcnt vmcnt(4)" ::: "memory");
  __builtin_amdgcn_s_barrier();
  asm volatile("" ::: "memory");

  for (int t = 0; t < NT; ++t){
    const unsigned short* bufc = &lds[(t % 3) * 8192];
    bf16x8 afr[4], bfr[4];
    #pragma unroll
    for (int i = 0; i < 4; ++i)
      afr[i] = *(const bf16x8*)&bufc[(wm * 64 + i * 16) * 32 + rsel];
    #pragma unroll
    for (int c = 0; c < 4; ++c)
      bfr[c] = *(const bf16x8*)&bufc[4096 + (wn * 64 + c * 16) * 32 + rsel];
    if (t + 2 < NT) STAGE4(t + 2, (t + 2) % 3)
    __builtin_amdgcn_s_setprio(1);
    #pragma unroll
    for (int i = 0; i < 4; ++i)
      #pragma unroll
      for (int c = 0; c < 4; ++c)
        acc[i][c] = mfma16(afr[i], bfr[c], acc[i][c]);
    __builtin_amdgcn_s_setprio(0);
    if (t + 2 < NT)      asm volatile("s_waitcnt vmcnt(4)" ::: "memory");
    else if (t + 1 < NT) asm volatile("s_waitcnt vmcnt(0)" ::: "memory");
    asm volatile("" ::: "memory");
    __builtin_amdgcn_s_barrier();
    asm volatile("" ::: "memory");
  }
  #undef STAGE4

  int r0 = bm + wm * 64 + ((lane >> 4) << 2);
  int c0 = bn + wn * 64 + (lane & 15);
  #pragma unroll
  for (int i = 0; i < 4; ++i){
    #pragma unroll
    for (int j = 0; j < 4; ++j){
      int cc = c0 + j * 16;
      if (cc < N){
        #pragma unroll
        for (int e = 0; e < 4; ++e){
          int rr = r0 + i * 16 + e;
          float v = acc[i][j][e];
          if (Cf){
            size_t idx = (size_t)rr * N + cc;
            if (addsrc) v += addsrc[idx];
            Cf[idx] = v;
          } else if (cc < splitN){
            Cb[(size_t)rr * splitN + cc] = f2b(v);
          } else {
            Cb2[(size_t)rr * (N - splitN) + (cc - splitN)] = f2b(v);
            if (dtraw && cc >= N - NH) dtraw[(size_t)rr * NH + (cc - (N - NH))] = v;
          }
        }
      }
    }
  }
}

// ---------------- fused dt-softplus + per-chunk cumsum of dA = dt*A ----------------
__global__ __launch_bounds__(64) void acum_kernel(const float* __restrict__ dtraw,
                                                  const float* __restrict__ dt_bias,
                                                  const float* __restrict__ A_log,
                                                  float* __restrict__ dtb,
                                                  float* __restrict__ acum)
{
  int bid = blockIdx.x;
  int c = bid & 15;
  int hh = (bid >> 4) & 63;
  int b = bid >> 10;
  int lane = threadIdx.x;
  float Av = -expf(A_log[hh]);
  float bias = dt_bias[hh];
  int rowbase = b * LTOT + c * CHUNK_;
  float r0 = dtraw[(size_t)(rowbase + 2 * lane) * NH + hh] + bias;
  float r1 = dtraw[(size_t)(rowbase + 2 * lane + 1) * NH + hh] + bias;
  float d0 = (r0 > 20.f) ? r0 : log1pf(expf(r0));
  float d1 = (r1 > 20.f) ? r1 : log1pf(expf(r1));
  dtb[(size_t)(rowbase + 2 * lane) * NH + hh] = d0;
  dtb[(size_t)(rowbase + 2 * lane + 1) * NH + hh] = d1;
  float v0 = d0 * Av, v1 = d1 * Av;
  float s = v0 + v1;
  #pragma unroll
  for (int d = 1; d < 64; d <<= 1){
    float t = __shfl_up(s, d, 64);
    if (lane >= d) s += t;
  }
  float excl = s - (v0 + v1);
  float* dst = acum + ((size_t)(b * NH + hh)) * LTOT + c * CHUNK_;
  dst[2 * lane]     = excl + v0;
  dst[2 * lane + 1] = excl + v0 + v1;
}

// ---------------- depthwise causal conv (width 4) + bias + SiLU; 4 l's per thread ----------------
__global__ __launch_bounds__(256) void conv_kernel(const unsigned short* __restrict__ xdt,
                                                   const float* __restrict__ cw,
                                                   const float* __restrict__ cb,
                                                   unsigned short* __restrict__ xbc)
{
  int ch = blockIdx.x * 256 + threadIdx.x;
  int l0 = blockIdx.y * 4, b = blockIdx.z;
  float x[7];
  #pragma unroll
  for (int j = 0; j < 7; j++){
    int ls = l0 - 3 + j;
    x[j] = (ls >= 0) ? b2f(xdt[((size_t)(b * LTOT + ls)) * XDTC + ch]) : 0.f;
  }
  float w0 = cw[ch * 4 + 0], w1 = cw[ch * 4 + 1], w2 = cw[ch * 4 + 2], w3 = cw[ch * 4 + 3];
  float bias = cb[ch];
  #pragma unroll
  for (int i = 0; i < 4; i++){
    float acc = bias + x[i] * w0 + x[i + 1] * w1 + x[i + 2] * w2 + x[i + 3] * w3;
    acc = acc / (1.f + expf(-acc));
    xbc[((size_t)(b * LTOT + l0 + i)) * CONVD + ch] = f2b(acc);
  }
}

// ---------------- SSD part 2: states[p][n] = sum_l (x*dt*decay)[l][p] * B[l][n] ----------------
__global__ __launch_bounds__(256) void ssd_states_kernel(const unsigned short* __restrict__ xbc,
                                                         const float* __restrict__ dtb,
                                                         const float* __restrict__ acum,
                                                         unsigned short* __restrict__ states)
{
  int hh = blockIdx.x, c = blockIdx.y, b = blockIdx.z;
  __shared__ unsigned short BsT[128][136];  // [n][l]
  __shared__ unsigned short XT[64][136];    // [p][l]
  __shared__ float ac[128];
  int tid = threadIdx.x, lane = tid & 63, w = tid >> 6;
  size_t rowbase = (size_t)b * LTOT + c * CHUNK_;
  if (tid < 128) ac[tid] = acum[((size_t)(b * NH + hh)) * LTOT + c * CHUNK_ + tid];
  #pragma unroll
  for (int p = 0; p < 16; p++){
    int l = p * 8 + (tid >> 5);
    int n4 = (tid & 31) * 4;
    u16x4 v = *(const u16x4*)&xbc[(rowbase + l) * CONVD + DINNER + n4];
    BsT[n4 + 0][l] = v[0];
    BsT[n4 + 1][l] = v[1];
    BsT[n4 + 2][l] = v[2];
    BsT[n4 + 3][l] = v[3];
  }
  #pragma unroll
  for (int p = 0; p < 8; p++){
    int l = p * 16 + (tid >> 4);
    int p4 = (tid & 15) * 4;
    float dtl = dtb[(rowbase + l) * NH + hh];
    u16x4 v = *(const u16x4*)&xbc[(rowbase + l) * CONVD + hh * HD + p4];
    XT[p4 + 0][l] = f2b(b2f(v[0]) * dtl);
    XT[p4 + 1][l] = f2b(b2f(v[1]) * dtl);
    XT[p4 + 2][l] = f2b(b2f(v[2]) * dtl);
    XT[p4 + 3][l] = f2b(b2f(v[3]) * dtl);
  }
  __syncthreads();
  float aclast = ac[127];
  f32x4 accP[8] = {};
  #pragma unroll
  for (int kk = 0; kk < 4; kk++){
    int kbase = kk * 32 + (lane >> 4) * 8;
    union { u16x4 q[2]; unsigned short u[8]; bf16x8 v; } rw, ot;
    rw.q[0] = *(const u16x4*)&XT[w * 16 + (lane & 15)][kbase];
    rw.q[1] = *(const u16x4*)&XT[w * 16 + (lane & 15)][kbase + 4];
    #pragma unroll
    for (int e = 0; e < 8; e++){
      ot.u[e] = f2b(b2f(rw.u[e]) * expf(aclast - ac[kbase + e]));
    }
    #pragma unroll
    for (int fc = 0; fc < 8; fc++){
      bf16x8 bb = *(const bf16x8*)&BsT[fc * 16 + (lane & 15)][kbase];
      accP[fc] = mfma16(ot.v, bb, accP[fc]);
    }
  }
  size_t sbase = ((size_t)((b * NCH + c) * NH + hh)) * HD * DSTATE;
  int p0 = w * 16 + ((lane >> 4) << 2);
  #pragma unroll
  for (int fc = 0; fc < 8; fc++){
    int n = fc * 16 + (lane & 15);
    #pragma unroll
    for (int j = 0; j < 4; j++){
      states[sbase + (size_t)(p0 + j) * DSTATE + n] = f2b(accP[fc][j]);
    }
  }
}

// ---------------- SSD part 3: inter-chunk scan, in-place states -> prev; j split 8x ----------------
__global__ __launch_bounds__(256) void scan_kernel(unsigned short* __restrict__ states,
                                                   const float* __restrict__ acum)
{
  int bh = blockIdx.x;
  int b = bh >> 6, hh = bh & 63;
  int jg = blockIdx.y * 4;
  int t = threadIdx.x;
  float run[4] = {0.f, 0.f, 0.f, 0.f};
  for (int c = 0; c < NCH; c++){
    float alast = acum[(size_t)bh * LTOT + c * CHUNK_ + 127];
    float dec = expf(alast);
    size_t base = ((size_t)((b * NCH + c) * NH + hh)) * (HD * DSTATE);
    #pragma unroll
    for (int j = 0; j < 4; j++){
      size_t idx = base + (size_t)(jg + j) * 256 + t;
      float sc = b2f(states[idx]);
      states[idx] = f2b(run[j]);
      run[j] = run[j] * dec + sc;
    }
  }
}

// ---------------- FUSED SSD-Y: y = Y_diag + Y_off + D*x, one bf16 write (R14-verified) ---------
__global__ __launch_bounds__(256, 2) void ssd_y_kernel(const unsigned short* __restrict__ xbc,
                                                       const unsigned short* __restrict__ states,
                                                       const float* __restrict__ dtb,
                                                       const float* __restrict__ acum,
                                                       const float* __restrict__ Dp,
                                                       unsigned short* __restrict__ y)
{
  extern __shared__ unsigned short lds[];
  unsigned short* Cs = lds;                 // [64][136]
  unsigned short* Bs = lds + 8704;          // [128][136]
  unsigned short* Ps = lds + 26112;         // [64][136]
  float* ac = (float*)(lds + 34816);        // [128]
  #define CS(r, cix) Cs[(r) * 136 + (cix)]
  #define BS(r, cix) Bs[(r) * 136 + (cix)]
  #define PS(r, cix) Ps[(r) * 136 + (cix)]
  int hh = blockIdx.x;
  int c = blockIdx.y >> 1;
  int half = blockIdx.y & 1;
  int b = blockIdx.z;
  int tid = threadIdx.x, lane = tid & 63, w = tid >> 6;
  int l0 = half * 64;
  size_t rowbase = (size_t)b * LTOT + c * CHUNK_;
  if (tid < 128) ac[tid] = acum[((size_t)(b * NH + hh)) * LTOT + c * CHUNK_ + tid];
  #pragma unroll
  for (int p = 0; p < 8; p++){
    int lr = p * 8 + (tid >> 5);
    int n4 = (tid & 31) * 4;
    *(u16x4*)&CS(lr, n4) =
      *(const u16x4*)&xbc[(rowbase + l0 + lr) * CONVD + DINNER + DSTATE + n4];
  }
  #pragma unroll
  for (int p = 0; p < 16; p++){
    int s = p * 8 + (tid >> 5);
    int n4 = (tid & 31) * 4;
    *(u16x4*)&BS(s, n4) = *(const u16x4*)&xbc[(rowbase + s) * CONVD + DINNER + n4];
  }
  size_t sbase = ((size_t)((b * NCH + c) * NH + hh)) * (HD * DSTATE);
  #pragma unroll
  for (int p = 0; p < 8; p++){
    int pp = p * 8 + (tid >> 5);
    int n4 = (tid & 31) * 4;
    *(u16x4*)&PS(pp, n4) = *(const u16x4*)&states[sbase + (size_t)pp * DSTATE + n4];
  }
  __syncthreads();
  f32x4 accS[8] = {};
  #pragma unroll
  for (int kk = 0; kk < 4; kk++){
    bf16x8 a = *(const bf16x8*)&CS(w * 16 + (lane & 15), kk * 32 + (lane >> 4) * 8);
    #pragma unroll
    for (int fc = 0; fc < 8; fc++){
      bf16x8 bb = *(const bf16x8*)&BS(fc * 16 + (lane & 15), kk * 32 + (lane >> 4) * 8);
      accS[fc] = mfma16(a, bb, accS[fc]);
    }
  }
  f32x4 accY[4] = {};
  {
    int arow = w * 16 + (lane & 15);
    float el = expf(ac[l0 + arow]);
    #pragma unroll
    for (int kk = 0; kk < 4; kk++){
      int kbase = kk * 32 + (lane >> 4) * 8;
      union { u16x4 q[2]; unsigned short u[8]; bf16x8 v; } cf;
      cf.q[0] = *(const u16x4*)&CS(arow, kbase);
      cf.q[1] = *(const u16x4*)&CS(arow, kbase + 4);
      #pragma unroll
      for (int e = 0; e < 8; e++) cf.u[e] = f2b(b2f(cf.u[e]) * el);
      #pragma unroll
      for (int fc = 0; fc < 4; fc++){
        bf16x8 bb = *(const bf16x8*)&PS(fc * 16 + (lane & 15), kbase);
        accY[fc] = mfma16(cf.v, bb, accY[fc]);
      }
    }
  }
  __syncthreads();
  {
    int lr = w * 16 + ((lane >> 4) << 2);
    #pragma unroll
    for (int fc = 0; fc < 8; fc++){
      int s = fc * 16 + (lane & 15);
      #pragma unroll
      for (int j = 0; j < 4; j++){
        int l = l0 + lr + j;
        float v = (s <= l) ? accS[fc][j] * expf(ac[l] - ac[s]) : 0.f;
        CS(lr + j, s) = f2b(v);
      }
    }
  }
  #pragma unroll
  for (int p = 0; p < 8; p++){
    int lr = p * 16 + (tid >> 4);
    int p4 = (tid & 15) * 4;
    float dtl = dtb[(rowbase + lr) * NH + hh];
    u16x4 v = *(const u16x4*)&xbc[(rowbase + lr) * CONVD + hh * HD + p4];
    BS(p4 + 0, lr) = f2b(b2f(v[0]) * dtl);
    BS(p4 + 1, lr) = f2b(b2f(v[1]) * dtl);
    BS(p4 + 2, lr) = f2b(b2f(v[2]) * dtl);
    BS(p4 + 3, lr) = f2b(b2f(v[3]) * dtl);
  }
  __syncthreads();
  #pragma unroll
  for (int kk = 0; kk < 4; kk++){
    bf16x8 a = *(const bf16x8*)&CS(w * 16 + (lane & 15), kk * 32 + (lane >> 4) * 8);
    #pragma unroll
    for (int fc = 0; fc < 4; fc++){
      bf16x8 bb = *(const bf16x8*)&BS(fc * 16 + (lane & 15), kk * 32 + (lane >> 4) * 8);
      accY[fc] = mfma16(a, bb, accY[fc]);
    }
  }
  float dpar = Dp[hh];
  {
    int lr = w * 16 + ((lane >> 4) << 2);
    #pragma unroll
    for (int fc = 0; fc < 4; fc++){
      int p = fc * 16 + (lane & 15);
      #pragma unroll
      for (int j = 0; j < 4; j++){
        int l = l0 + lr + j;
        float xsv = b2f(xbc[(rowbase + l) * CONVD + hh * HD + p]);
        y[(rowbase + l) * DINNER + hh * HD + p] = f2b(accY[fc][j] + dpar * xsv);
      }
    }
  }
  #undef CS
  #undef BS
  #undef PS
}

extern "C" void kernel_launch(void* const* d_in, const int* in_sizes, int n_in,
                              void* d_out, int out_size, void* d_ws, size_t ws_size,
                              hipStream_t stream)
{
  (void)in_sizes; (void)n_in; (void)out_size; (void)ws_size;
  const float* hidden    = (const float*)d_in[0];
  const float* norm1_w   = (const float*)d_in[1];
  const float* in_proj_w = (const float*)d_in[2];
  const float* conv_w    = (const float*)d_in[3];
  const float* conv_b    = (const float*)d_in[4];
  const float* dt_bias   = (const float*)d_in[5];
  const float* A_log     = (const float*)d_in[6];
  const float* D_param   = (const float*)d_in[7];
  const float* mixer_w   = (const float*)d_in[8];
  const float* out_proj_w= (const float*)d_in[9];
  const float* norm2_w   = (const float*)d_in[10];
  const float* gate_w    = (const float*)d_in[11];
  const float* up_w      = (const float*)d_in[12];
  const float* down_w    = (const float*)d_in[13];

  char* ws = (char*)d_ws;
  unsigned short* zbuf    = (unsigned short*)(ws);                  // bf16 4096x4096 [k2..k10]
  unsigned short* WT_cat  = (unsigned short*)(ws);                  // bf16 11264x2048 interleaved [k12.5..k13]
  unsigned short* WT_down = (unsigned short*)(ws);                  // bf16 2048x5632 [k14..k15]
  unsigned short* xdt     = (unsigned short*)(ws + 33554432ull);    // bf16 4096x4416 [k2..k5]
  unsigned short* states  = (unsigned short*)(ws + 33554432ull);    // bf16 16.7M el  [k7..k9]
  unsigned short* ygn     = (unsigned short*)(ws + 33554432ull);    // bf16 4096x4096 [k10..k11]
  unsigned short* xbc     = (unsigned short*)(ws + 69730304ull);    // bf16 4096x4352 [k5..k9]
  unsigned short* WT_out  = (unsigned short*)(ws + 69730304ull);    // bf16 2048x4096 [k10.5..k11]
  float* dtraw            = (float*)(ws + 105381888ull);            // f32 4096x64 [k2..k3]
  float* dtb              = (float*)(ws + 106430464ull);            // f32 4096x64 [k3..k9]
  float* acum             = (float*)(ws + 107479040ull);            // f32 128x2048 [k4..k9]
  unsigned short* ybb     = (unsigned short*)(ws + 108527616ull);   // bf16 4096x4096 [k6..k10]
  unsigned short* hbuf    = (unsigned short*)(ws + 108527616ull);   // bf16 4096x2048 [k1..k2]
  unsigned short* gbuf    = (unsigned short*)(ws + 108527616ull);   // bf16 4096x5632 [k13..k15]
  unsigned short* WT_in   = (unsigned short*)(ws + 125304832ull);   // bf16 8704x2048 [k0..k2]
  unsigned short* h2      = (unsigned short*)(ws + 154664960ull);   // bf16 4096x2048 [k12..k13]
  float* h1               = (float*)d_out;
  float* outp             = (float*)d_out;

  const int dynLDS3 = 73728;   // 3 x 24KB -> 2 blocks/CU
  const int dynLDS4 = 49152;   // 3 x 16KB -> 3 blocks/CU
  const int dynLDSY = 70144;   // Cs+Bs+Ps+ac -> 2 blocks/CU
  hipFuncSetAttribute((const void*)gemm3_kernel,
                      hipFuncAttributeMaxDynamicSharedMemorySize, dynLDS3);
  hipFuncSetAttribute((const void*)gemm4_kernel,
                      hipFuncAttributeMaxDynamicSharedMemorySize, dynLDS4);
  hipFuncSetAttribute((const void*)ssd_y_kernel,
                      hipFuncAttributeMaxDynamicSharedMemorySize, dynLDSY);

  // 0. convert in_proj weight -> bf16 [8704][2048]
  wconv_kernel<<<dim3(136, 32), 256, 0, stream>>>(in_proj_w, WT_in, DMODEL, INP, 1, 0);
  // 1. h = rmsnorm(hidden) -> bf16
  rms_kernel<<<NTOK, 256, 0, stream>>>(hidden, norm1_w, hbuf, DMODEL);
  // 2. zxbcdt = h @ in_proj via gemm4: grid 68x32 = 2176 blocks @ 3/CU -> 94% round fill
  gemm4_kernel<<<dim3(68, 32), 256, dynLDS4, stream>>>(hbuf, WT_in, nullptr, nullptr,
                                                       zbuf, xdt, DINNER, dtraw,
                                                       NTOK, INP, DMODEL, 8);
  // 3+4. fused softplus + cumsum
  acum_kernel<<<BATCH * NH * NCH, 64, 0, stream>>>(dtraw, dt_bias, A_log, dtb, acum);
  // 5. conv + silu
  conv_kernel<<<dim3(CONVD / 256, LTOT / 4, BATCH), 256, 0, stream>>>(xdt, conv_w, conv_b, xbc);
  // 6. SSD per-chunk states
  ssd_states_kernel<<<dim3(NH, NCH, BATCH), 256, 0, stream>>>(xbc, dtb, acum, states);
  // 7. inter-chunk scan (in-place -> prev)
  scan_kernel<<<dim3(BATCH * NH, 8), 256, 0, stream>>>(states, acum);
  // 8. FUSED Y: Y_diag + Y_off + D*x -> ybb (bf16, one write)
  ssd_y_kernel<<<dim3(NH, NCH * 2, BATCH), 256, dynLDSY, stream>>>(xbc, states, dtb, acum,
                                                                   D_param, ybb);
  // 9. gated rmsnorm: ygn = rmsnorm(y * silu(z))
  rms_gated_kernel<<<NTOK, 256, 0, stream>>>(ybb, zbuf, mixer_w, ygn);
  // 9.5 convert out_proj weight
  wconv_kernel<<<dim3(32, 64), 256, 0, stream>>>(out_proj_w, WT_out, DINNER, DMODEL, 1, 0);
  // 10. h1 = hidden + ygn @ out_proj (into d_out)
  gemm4_kernel<<<dim3(16, 32), 256, dynLDS4, stream>>>(ygn, WT_out, hidden, h1,
                                                       nullptr, nullptr, 0, nullptr,
                                                       NTOK, DMODEL, DINNER, 4);
  // 11. h2 = rmsnorm(h1) -> bf16
  rms_kernel<<<NTOK, 256, 0, stream>>>(h1, norm2_w, h2, DMODEL);
  // 11.5 convert gate+up weights, column-interleaved
  wconv_kernel<<<dim3(88, 32), 256, 0, stream>>>(gate_w, WT_cat, DMODEL, INTER_, 2, 0);
  wconv_kernel<<<dim3(88, 32), 256, 0, stream>>>(up_w, WT_cat, DMODEL, INTER_, 2, 1);
  // 12. fused gate+up GEMM with GLU epilogue
  gemm3_kernel<<<dim3(44, 32), 512, dynLDS3, stream>>>(h2, WT_cat, nullptr, nullptr,
                                                       gbuf, nullptr, 0, 1, nullptr,
                                                       NTOK, 2 * INTER_, DMODEL);
  // 13. convert down weight
  wconv_kernel<<<dim3(32, 88), 256, 0, stream>>>(down_w, WT_down, INTER_, DMODEL, 1, 0);
  // 14. out = h1 + (g*u) @ down_w (in place on d_out)
  gemm4_kernel<<<dim3(16, 32), 256, dynLDS4, stream>>>(gbuf, WT_down, h1, outp,
                                                       nullptr, nullptr, 0, nullptr,
                                                       NTOK, DMODEL, INTER_, 4);
}

// Round 16
// 916.646 us; speedup vs baseline: 1.0071x; 1.0071x over previous
//
#include <hip/hip_runtime.h>

#define LTOT 2048
#define BATCH 2
#define NTOK 4096
#define DMODEL 2048
#define DSTATE 128
#define NH 64
#define HD 64
#define DINNER 4096
#define CONVD 4352
#define XDTC 4416
#define INP 8512
#define INTER_ 5632
#define CHUNK_ 128
#define NCH 16
#define EPSF 1e-6f

typedef __bf16 bf16x8 __attribute__((ext_vector_type(8)));
typedef float f32x4 __attribute__((ext_vector_type(4)));
typedef unsigned short u16x4 __attribute__((ext_vector_type(4)));
typedef unsigned short u16x8 __attribute__((ext_vector_type(8)));

__device__ __forceinline__ unsigned short f2b(float f){
  unsigned int u = __builtin_bit_cast(unsigned int, f);
  u += 0x7fffu + ((u >> 16) & 1u);
  return (unsigned short)(u >> 16);
}
__device__ __forceinline__ float b2f(unsigned short h){
  return __builtin_bit_cast(float, ((unsigned int)h) << 16);
}
__device__ __forceinline__ f32x4 mfma16(bf16x8 a, bf16x8 b, f32x4 c){
  return __builtin_amdgcn_mfma_f32_16x16x32_bf16(a, b, c, 0, 0, 0);
}
// async global->LDS, 16B per lane, wave-uniform LDS base + lane*16
typedef const __attribute__((address_space(1))) void* gas_t;
typedef __attribute__((address_space(3))) void* las_t;
__device__ __forceinline__ void gload16(const void* g, void* l){
  __builtin_amdgcn_global_load_lds((gas_t)g, (las_t)l, 16, 0, 0);
}

// ---------------- weight convert: fp32 W[K][N] -> bf16 WT[(n*rstride+roff)][K] ----------------
__global__ __launch_bounds__(256) void wconv_kernel(const float* __restrict__ W,
                                                    unsigned short* __restrict__ WT,
                                                    int K, int N, int rstride, int roff)
{
  __shared__ unsigned short t[64][72];
  int n0 = blockIdx.x * 64, k0 = blockIdx.y * 64;
  int tid = threadIdx.x;
  int kl = tid >> 4, nl4 = (tid & 15) * 4;
  #pragma unroll
  for (int it = 0; it < 4; it++){
    int kk = kl + it * 16;
    float4 v = make_float4(0.f, 0.f, 0.f, 0.f);
    if (n0 < N) v = *(const float4*)&W[(size_t)(k0 + kk) * N + n0 + nl4];
    t[nl4 + 0][kk] = f2b(v.x);
    t[nl4 + 1][kk] = f2b(v.y);
    t[nl4 + 2][kk] = f2b(v.z);
    t[nl4 + 3][kk] = f2b(v.w);
  }
  __syncthreads();
  int nr = tid >> 3, k8 = (tid & 7) * 8;
  #pragma unroll
  for (int it = 0; it < 2; it++){
    int nn = nr + it * 32;
    *(u16x8*)&WT[((size_t)(n0 + nn) * rstride + roff) * K + k0 + k8] = *(const u16x8*)&t[nn][k8];
  }
}

// ---------------- RMSNorm: fp32 in -> bf16 out ----------------
__global__ __launch_bounds__(256) void rms_kernel(const float* __restrict__ x,
                                                  const float* __restrict__ w,
                                                  unsigned short* __restrict__ out, int width)
{
  int row = blockIdx.x, tid = threadIdx.x;
  const float* xr = x + (size_t)row * width;
  unsigned short* orow = out + (size_t)row * width;
  int nv = width >> 2;
  float ss = 0.f;
  for (int i = tid; i < nv; i += 256){
    float4 v = ((const float4*)xr)[i];
    ss += v.x*v.x + v.y*v.y + v.z*v.z + v.w*v.w;
  }
  #pragma unroll
  for (int off = 32; off > 0; off >>= 1) ss += __shfl_down(ss, off, 64);
  __shared__ float red[4];
  if ((tid & 63) == 0) red[tid >> 6] = ss;
  __syncthreads();
  float tot = red[0] + red[1] + red[2] + red[3];
  float scale = rsqrtf(tot / (float)width + EPSF);
  for (int i = tid; i < nv; i += 256){
    float4 v = ((const float4*)xr)[i];
    float4 wv = ((const float4*)w)[i];
    u16x4 o = { f2b(v.x * scale * wv.x), f2b(v.y * scale * wv.y),
                f2b(v.z * scale * wv.z), f2b(v.w * scale * wv.w) };
    ((u16x4*)orow)[i] = o;
  }
}

// ---------------- Gated RMSNorm: y bf16, z bf16 -> out bf16 ----------------
__global__ __launch_bounds__(256) void rms_gated_kernel(const unsigned short* __restrict__ y,
                                                        const unsigned short* __restrict__ z,
                                                        const float* __restrict__ w,
                                                        unsigned short* __restrict__ out)
{
  int row = blockIdx.x, tid = threadIdx.x;
  const unsigned short* yr = y + (size_t)row * DINNER;
  const unsigned short* zr = z + (size_t)row * DINNER;
  unsigned short* orow = out + (size_t)row * DINNER;
  float g[16];
  float ss = 0.f;
  #pragma unroll
  for (int ii = 0; ii < 4; ii++){
    int i = tid + ii * 256;
    u16x4 yv = ((const u16x4*)yr)[i];
    u16x4 zv = ((const u16x4*)zr)[i];
    #pragma unroll
    for (int e = 0; e < 4; e++){
      float zf = b2f(zv[e]);
      float yf = b2f(yv[e]);
      float gg = yf * (zf / (1.f + expf(-zf)));
      g[ii * 4 + e] = gg;
      ss += gg * gg;
    }
  }
  #pragma unroll
  for (int off = 32; off > 0; off >>= 1) ss += __shfl_down(ss, off, 64);
  __shared__ float red[4];
  if ((tid & 63) == 0) red[tid >> 6] = ss;
  __syncthreads();
  float tot = red[0] + red[1] + red[2] + red[3];
  float scale = rsqrtf(tot / (float)DINNER + EPSF);
  #pragma unroll
  for (int ii = 0; ii < 4; ii++){
    int i = tid + ii * 256;
    float4 wv = ((const float4*)w)[i];
    u16x4 o;
    #pragma unroll
    for (int e = 0; e < 4; e++) o[e] = f2b(g[ii * 4 + e] * scale * (&wv.x)[e]);
    ((u16x4*)orow)[i] = o;
  }
}

// ---------------- GEMM3: 128(M)x256(N), BK=32, 8 waves, 3x24KB bufs -> 2 blocks/CU -------------
// Measured-best config (R14). A/B this round: NO setprio (T5 null-to-negative on non-phase-split
// GEMMs, m190; 2-block/CU overlap may prefer unbiased scheduling).
__global__ __launch_bounds__(512, 2) void gemm3_kernel(const unsigned short* __restrict__ A,
                                                       const unsigned short* __restrict__ BT,
                                                       const float* __restrict__ addsrc,
                                                       float* __restrict__ Cf,
                                                       unsigned short* __restrict__ Cb,
                                                       unsigned short* __restrict__ Cb2, int splitN,
                                                       int glu,
                                                       float* __restrict__ dtraw,
                                                       int M, int N, int K)
{
  extern __shared__ unsigned short lds[];
  int tid = threadIdx.x, lane = tid & 63, w = tid >> 6;
  int wm = w >> 2, wn = w & 3;
  int bid = blockIdx.x + blockIdx.y * gridDim.x;
  int nwg = gridDim.x * gridDim.y;
  int q8 = nwg >> 3, r8 = nwg & 7;
  int xcd = bid & 7, boff = bid >> 3;
  int wgid = (xcd < r8 ? xcd * (q8 + 1) : r8 * (q8 + 1) + (xcd - r8) * q8) + boff;
  int gsz = 8 * gridDim.x;
  int grp = wgid / gsz, rem = wgid % gsz;
  int bm = (grp * 8 + (rem & 7)) * 128;
  int bn = (rem >> 3) * 256;

  int gsrc = (((lane & 3) ^ ((lane >> 2) & 3) ^ ((4 * w + (lane >> 4)) & 3)) << 3);
  int prow_l = lane >> 2;
  int ko = (((lane >> 4) ^ (lane & 3) ^ ((lane >> 2) & 3)) << 3);
  int rsel = (lane & 15) * 32 + ko;

  const unsigned short* pA  = A  + (size_t)(bm +       w * 16 + prow_l) * K + gsrc;
  const unsigned short* pB0 = BT + (size_t)(bn +       w * 16 + prow_l) * K + gsrc;
  const unsigned short* pB1 = BT + (size_t)(bn + 128 + w * 16 + prow_l) * K + gsrc;

  f32x4 acc[4][4] = {};
  int NT = K >> 5;

  #define STAGE(kt, bsel)                                                              \
    {                                                                                  \
      unsigned short* bb_ = &lds[(bsel) * 12288];                                      \
      size_t kof_ = (size_t)(kt) << 5;                                                 \
      gload16(pA  + kof_, &bb_[w * 512]);                                              \
      gload16(pB0 + kof_, &bb_[4096 + w * 512]);                                       \
      gload16(pB1 + kof_, &bb_[8192 + w * 512]);                                       \
    }

  STAGE(0, 0)
  STAGE(1, 1)
  asm volatile("s_waitcnt vmcnt(3)" ::: "memory");
  __builtin_amdgcn_s_barrier();
  asm volatile("" ::: "memory");

  for (int t = 0; t < NT; ++t){
    const unsigned short* bufc = &lds[(t % 3) * 12288];
    bf16x8 afr[4], bfr[4];
    #pragma unroll
    for (int i = 0; i < 4; ++i)
      afr[i] = *(const bf16x8*)&bufc[(wm * 64 + i * 16) * 32 + rsel];
    #pragma unroll
    for (int c = 0; c < 4; ++c)
      bfr[c] = *(const bf16x8*)&bufc[4096 + (wn * 64 + c * 16) * 32 + rsel];
    if (t + 2 < NT) STAGE(t + 2, (t + 2) % 3)
    #pragma unroll
    for (int i = 0; i < 4; ++i)
      #pragma unroll
      for (int c = 0; c < 4; ++c)
        acc[i][c] = mfma16(afr[i], bfr[c], acc[i][c]);
    if (t + 2 < NT)      asm volatile("s_waitcnt vmcnt(3)" ::: "memory");
    else if (t + 1 < NT) asm volatile("s_waitcnt vmcnt(0)" ::: "memory");
    asm volatile("" ::: "memory");
    __builtin_amdgcn_s_barrier();
    asm volatile("" ::: "memory");
  }
  #undef STAGE

  int r0 = bm + wm * 64 + ((lane >> 4) << 2);
  int c0 = bn + wn * 64 + (lane & 15);
  #pragma unroll
  for (int i = 0; i < 4; ++i){
    #pragma unroll
    for (int j = 0; j < 4; ++j){
      int cc = c0 + j * 16;
      if (glu){
        #pragma unroll
        for (int e = 0; e < 4; ++e){
          float v = acc[i][j][e];
          float pv = __shfl_xor(v, 1, 64);
          if (!(lane & 1)){
            int rr = r0 + i * 16 + e;
            float res = v / (1.f + expf(-v)) * pv;   // silu(gate)*up
            Cb[(size_t)rr * (N >> 1) + (cc >> 1)] = f2b(res);
          }
        }
      } else if (cc < N){
        #pragma unroll
        for (int e = 0; e < 4; ++e){
          int rr = r0 + i * 16 + e;
          float v = acc[i][j][e];
          if (Cf){
            size_t idx = (size_t)rr * N + cc;
            if (addsrc) v += addsrc[idx];
            Cf[idx] = v;
          } else if (cc < splitN){
            Cb[(size_t)rr * splitN + cc] = f2b(v);
          } else {
            Cb2[(size_t)rr * (N - splitN) + (cc - splitN)] = f2b(v);
            if (dtraw && cc >= N - NH) dtraw[(size_t)rr * NH + (cc - (N - NH))] = v;
          }
        }
      }
    }
  }
}

// ---------------- GEMM4: 128x128, BK=32, 4 waves, 3x16KB bufs -> 3 blocks/CU (setprio kept) ----
__global__ __launch_bounds__(256, 3) void gemm4_kernel(const unsigned short* __restrict__ A,
                                                       const unsigned short* __restrict__ BT,
                                                       const float* __restrict__ addsrc,
                                                       float* __restrict__ Cf,
                                                       int M, int N, int K, int GM)
{
  extern __shared__ unsigned short lds[];
  int tid = threadIdx.x, lane = tid & 63, w = tid >> 6;
  int wm = w >> 1, wn = w & 1;
  int bid = blockIdx.x + blockIdx.y * gridDim.x;
  int nwg = gridDim.x * gridDim.y;
  int q8 = nwg >> 3, r8 = nwg & 7;
  int xcd = bid & 7, boff = bid >> 3;
  int wgid = (xcd < r8 ? xcd * (q8 + 1) : r8 * (q8 + 1) + (xcd - r8) * q8) + boff;
  int gsz = GM * gridDim.x;
  int grp = wgid / gsz, rem = wgid % gsz;
  int bm = (grp * GM + (rem % GM)) * 128;
  int bn = (rem / GM) * 128;

  int gsrc = (((lane & 3) ^ ((lane >> 2) & 3) ^ ((4 * w + (lane >> 4)) & 3)) << 3);
  int prow_l = lane >> 2;
  int ko = (((lane >> 4) ^ (lane & 3) ^ ((lane >> 2) & 3)) << 3);
  int rsel = (lane & 15) * 32 + ko;

  const unsigned short* pA0 = A  + (size_t)(bm +      w * 16 + prow_l) * K + gsrc;
  const unsigned short* pA1 = A  + (size_t)(bm + 64 + w * 16 + prow_l) * K + gsrc;
  const unsigned short* pB0 = BT + (size_t)(bn +      w * 16 + prow_l) * K + gsrc;
  const unsigned short* pB1 = BT + (size_t)(bn + 64 + w * 16 + prow_l) * K + gsrc;

  f32x4 acc[4][4] = {};
  int NT = K >> 5;

  #define STAGE4(kt, bsel)                                                             \
    {                                                                                  \
      unsigned short* bb_ = &lds[(bsel) * 8192];                                       \
      size_t kof_ = (size_t)(kt) << 5;                                                 \
      gload16(pA0 + kof_, &bb_[w * 512]);                                              \
      gload16(pA1 + kof_, &bb_[2048 + w * 512]);                                       \
      gload16(pB0 + kof_, &bb_[4096 + w * 512]);                                       \
      gload16(pB1 + kof_, &bb_[6144 + w * 512]);                                       \
    }

  STAGE4(0, 0)
  STAGE4(1, 1)
  asm volatile("s_waitcnt vmcnt(4)" ::: "memory");
  __builtin_amdgcn_s_barrier();
  asm volatile("" ::: "memory");

  for (int t = 0; t < NT; ++t){
    const unsigned short* bufc = &lds[(t % 3) * 8192];
    bf16x8 afr[4], bfr[4];
    #pragma unroll
    for (int i = 0; i < 4; ++i)
      afr[i] = *(const bf16x8*)&bufc[(wm * 64 + i * 16) * 32 + rsel];
    #pragma unroll
    for (int c = 0; c < 4; ++c)
      bfr[c] = *(const bf16x8*)&bufc[4096 + (wn * 64 + c * 16) * 32 + rsel];
    if (t + 2 < NT) STAGE4(t + 2, (t + 2) % 3)
    __builtin_amdgcn_s_setprio(1);
    #pragma unroll
    for (int i = 0; i < 4; ++i)
      #pragma unroll
      for (int c = 0; c < 4; ++c)
        acc[i][c] = mfma16(afr[i], bfr[c], acc[i][c]);
    __builtin_amdgcn_s_setprio(0);
    if (t + 2 < NT)      asm volatile("s_waitcnt vmcnt(4)" ::: "memory");
    else if (t + 1 < NT) asm volatile("s_waitcnt vmcnt(0)" ::: "memory");
    asm volatile("" ::: "memory");
    __builtin_amdgcn_s_barrier();
    asm volatile("" ::: "memory");
  }
  #undef STAGE4

  int r0 = bm + wm * 64 + ((lane >> 4) << 2);
  int c0 = bn + wn * 64 + (lane & 15);
  #pragma unroll
  for (int i = 0; i < 4; ++i){
    #pragma unroll
    for (int j = 0; j < 4; ++j){
      int cc = c0 + j * 16;
      #pragma unroll
      for (int e = 0; e < 4; ++e){
        int rr = r0 + i * 16 + e;
        size_t idx = (size_t)rr * N + cc;
        float v = acc[i][j][e];
        if (addsrc) v += addsrc[idx];
        Cf[idx] = v;
      }
    }
  }
}

// ---------------- fused dt-softplus + per-chunk cumsum of dA = dt*A ----------------
__global__ __launch_bounds__(64) void acum_kernel(const float* __restrict__ dtraw,
                                                  const float* __restrict__ dt_bias,
                                                  const float* __restrict__ A_log,
                                                  float* __restrict__ dtb,
                                                  float* __restrict__ acum)
{
  int bid = blockIdx.x;
  int c = bid & 15;
  int hh = (bid >> 4) & 63;
  int b = bid >> 10;
  int lane = threadIdx.x;
  float Av = -expf(A_log[hh]);
  float bias = dt_bias[hh];
  int rowbase = b * LTOT + c * CHUNK_;
  float r0 = dtraw[(size_t)(rowbase + 2 * lane) * NH + hh] + bias;
  float r1 = dtraw[(size_t)(rowbase + 2 * lane + 1) * NH + hh] + bias;
  float d0 = (r0 > 20.f) ? r0 : log1pf(expf(r0));
  float d1 = (r1 > 20.f) ? r1 : log1pf(expf(r1));
  dtb[(size_t)(rowbase + 2 * lane) * NH + hh] = d0;
  dtb[(size_t)(rowbase + 2 * lane + 1) * NH + hh] = d1;
  float v0 = d0 * Av, v1 = d1 * Av;
  float s = v0 + v1;
  #pragma unroll
  for (int d = 1; d < 64; d <<= 1){
    float t = __shfl_up(s, d, 64);
    if (lane >= d) s += t;
  }
  float excl = s - (v0 + v1);
  float* dst = acum + ((size_t)(b * NH + hh)) * LTOT + c * CHUNK_;
  dst[2 * lane]     = excl + v0;
  dst[2 * lane + 1] = excl + v0 + v1;
}

// ---------------- depthwise causal conv (width 4) + bias + SiLU; 4 l's per thread ----------------
__global__ __launch_bounds__(256) void conv_kernel(const unsigned short* __restrict__ xdt,
                                                   const float* __restrict__ cw,
                                                   const float* __restrict__ cb,
                                                   unsigned short* __restrict__ xbc)
{
  int ch = blockIdx.x * 256 + threadIdx.x;
  int l0 = blockIdx.y * 4, b = blockIdx.z;
  float x[7];
  #pragma unroll
  for (int j = 0; j < 7; j++){
    int ls = l0 - 3 + j;
    x[j] = (ls >= 0) ? b2f(xdt[((size_t)(b * LTOT + ls)) * XDTC + ch]) : 0.f;
  }
  float w0 = cw[ch * 4 + 0], w1 = cw[ch * 4 + 1], w2 = cw[ch * 4 + 2], w3 = cw[ch * 4 + 3];
  float bias = cb[ch];
  #pragma unroll
  for (int i = 0; i < 4; i++){
    float acc = bias + x[i] * w0 + x[i + 1] * w1 + x[i + 2] * w2 + x[i + 3] * w3;
    acc = acc / (1.f + expf(-acc));
    xbc[((size_t)(b * LTOT + l0 + i)) * CONVD + ch] = f2b(acc);
  }
}

// ---------------- SSD part 2: states[p][n] = sum_l (x*dt*decay)[l][p] * B[l][n] ----------------
__global__ __launch_bounds__(256) void ssd_states_kernel(const unsigned short* __restrict__ xbc,
                                                         const float* __restrict__ dtb,
                                                         const float* __restrict__ acum,
                                                         unsigned short* __restrict__ states)
{
  int hh = blockIdx.x, c = blockIdx.y, b = blockIdx.z;
  __shared__ unsigned short BsT[128][136];  // [n][l]
  __shared__ unsigned short XT[64][136];    // [p][l]
  __shared__ float ac[128];
  int tid = threadIdx.x, lane = tid & 63, w = tid >> 6;
  size_t rowbase = (size_t)b * LTOT + c * CHUNK_;
  if (tid < 128) ac[tid] = acum[((size_t)(b * NH + hh)) * LTOT + c * CHUNK_ + tid];
  #pragma unroll
  for (int p = 0; p < 16; p++){
    int l = p * 8 + (tid >> 5);
    int n4 = (tid & 31) * 4;
    u16x4 v = *(const u16x4*)&xbc[(rowbase + l) * CONVD + DINNER + n4];
    BsT[n4 + 0][l] = v[0];
    BsT[n4 + 1][l] = v[1];
    BsT[n4 + 2][l] = v[2];
    BsT[n4 + 3][l] = v[3];
  }
  #pragma unroll
  for (int p = 0; p < 8; p++){
    int l = p * 16 + (tid >> 4);
    int p4 = (tid & 15) * 4;
    float dtl = dtb[(rowbase + l) * NH + hh];
    u16x4 v = *(const u16x4*)&xbc[(rowbase + l) * CONVD + hh * HD + p4];
    XT[p4 + 0][l] = f2b(b2f(v[0]) * dtl);
    XT[p4 + 1][l] = f2b(b2f(v[1]) * dtl);
    XT[p4 + 2][l] = f2b(b2f(v[2]) * dtl);
    XT[p4 + 3][l] = f2b(b2f(v[3]) * dtl);
  }
  __syncthreads();
  float aclast = ac[127];
  f32x4 accP[8] = {};
  #pragma unroll
  for (int kk = 0; kk < 4; kk++){
    int kbase = kk * 32 + (lane >> 4) * 8;
    union { u16x4 q[2]; unsigned short u[8]; bf16x8 v; } rw, ot;
    rw.q[0] = *(const u16x4*)&XT[w * 16 + (lane & 15)][kbase];
    rw.q[1] = *(const u16x4*)&XT[w * 16 + (lane & 15)][kbase + 4];
    #pragma unroll
    for (int e = 0; e < 8; e++){
      ot.u[e] = f2b(b2f(rw.u[e]) * expf(aclast - ac[kbase + e]));
    }
    #pragma unroll
    for (int fc = 0; fc < 8; fc++){
      bf16x8 bb = *(const bf16x8*)&BsT[fc * 16 + (lane & 15)][kbase];
      accP[fc] = mfma16(ot.v, bb, accP[fc]);
    }
  }
  size_t sbase = ((size_t)((b * NCH + c) * NH + hh)) * HD * DSTATE;
  int p0 = w * 16 + ((lane >> 4) << 2);
  #pragma unroll
  for (int fc = 0; fc < 8; fc++){
    int n = fc * 16 + (lane & 15);
    #pragma unroll
    for (int j = 0; j < 4; j++){
      states[sbase + (size_t)(p0 + j) * DSTATE + n] = f2b(accP[fc][j]);
    }
  }
}

// ---------------- SSD part 3: inter-chunk scan, in-place states -> prev; j split 8x ----------------
__global__ __launch_bounds__(256) void scan_kernel(unsigned short* __restrict__ states,
                                                   const float* __restrict__ acum)
{
  int bh = blockIdx.x;
  int b = bh >> 6, hh = bh & 63;
  int jg = blockIdx.y * 4;
  int t = threadIdx.x;
  float run[4] = {0.f, 0.f, 0.f, 0.f};
  for (int c = 0; c < NCH; c++){
    float alast = acum[(size_t)bh * LTOT + c * CHUNK_ + 127];
    float dec = expf(alast);
    size_t base = ((size_t)((b * NCH + c) * NH + hh)) * (HD * DSTATE);
    #pragma unroll
    for (int j = 0; j < 4; j++){
      size_t idx = base + (size_t)(jg + j) * 256 + t;
      float sc = b2f(states[idx]);
      states[idx] = f2b(run[j]);
      run[j] = run[j] * dec + sc;
    }
  }
}

// ---------------- FUSED SSD-Y: y = Y_diag + Y_off + D*x, one bf16 write (R14-verified) ---------
__global__ __launch_bounds__(256, 2) void ssd_y_kernel(const unsigned short* __restrict__ xbc,
                                                       const unsigned short* __restrict__ states,
                                                       const float* __restrict__ dtb,
                                                       const float* __restrict__ acum,
                                                       const float* __restrict__ Dp,
                                                       unsigned short* __restrict__ y)
{
  extern __shared__ unsigned short lds[];
  unsigned short* Cs = lds;                 // [64][136]
  unsigned short* Bs = lds + 8704;          // [128][136]
  unsigned short* Ps = lds + 26112;         // [64][136]
  float* ac = (float*)(lds + 34816);        // [128]
  #define CS(r, cix) Cs[(r) * 136 + (cix)]
  #define BS(r, cix) Bs[(r) * 136 + (cix)]
  #define PS(r, cix) Ps[(r) * 136 + (cix)]
  int hh = blockIdx.x;
  int c = blockIdx.y >> 1;
  int half = blockIdx.y & 1;
  int b = blockIdx.z;
  int tid = threadIdx.x, lane = tid & 63, w = tid >> 6;
  int l0 = half * 64;
  size_t rowbase = (size_t)b * LTOT + c * CHUNK_;
  if (tid < 128) ac[tid] = acum[((size_t)(b * NH + hh)) * LTOT + c * CHUNK_ + tid];
  #pragma unroll
  for (int p = 0; p < 8; p++){
    int lr = p * 8 + (tid >> 5);
    int n4 = (tid & 31) * 4;
    *(u16x4*)&CS(lr, n4) =
      *(const u16x4*)&xbc[(rowbase + l0 + lr) * CONVD + DINNER + DSTATE + n4];
  }
  #pragma unroll
  for (int p = 0; p < 16; p++){
    int s = p * 8 + (tid >> 5);
    int n4 = (tid & 31) * 4;
    *(u16x4*)&BS(s, n4) = *(const u16x4*)&xbc[(rowbase + s) * CONVD + DINNER + n4];
  }
  size_t sbase = ((size_t)((b * NCH + c) * NH + hh)) * (HD * DSTATE);
  #pragma unroll
  for (int p = 0; p < 8; p++){
    int pp = p * 8 + (tid >> 5);
    int n4 = (tid & 31) * 4;
    *(u16x4*)&PS(pp, n4) = *(const u16x4*)&states[sbase + (size_t)pp * DSTATE + n4];
  }
  __syncthreads();
  f32x4 accS[8] = {};
  #pragma unroll
  for (int kk = 0; kk < 4; kk++){
    bf16x8 a = *(const bf16x8*)&CS(w * 16 + (lane & 15), kk * 32 + (lane >> 4) * 8);
    #pragma unroll
    for (int fc = 0; fc < 8; fc++){
      bf16x8 bb = *(const bf16x8*)&BS(fc * 16 + (lane & 15), kk * 32 + (lane >> 4) * 8);
      accS[fc] = mfma16(a, bb, accS[fc]);
    }
  }
  f32x4 accY[4] = {};
  {
    int arow = w * 16 + (lane & 15);
    float el = expf(ac[l0 + arow]);
    #pragma unroll
    for (int kk = 0; kk < 4; kk++){
      int kbase = kk * 32 + (lane >> 4) * 8;
      union { u16x4 q[2]; unsigned short u[8]; bf16x8 v; } cf;
      cf.q[0] = *(const u16x4*)&CS(arow, kbase);
      cf.q[1] = *(const u16x4*)&CS(arow, kbase + 4);
      #pragma unroll
      for (int e = 0; e < 8; e++) cf.u[e] = f2b(b2f(cf.u[e]) * el);
      #pragma unroll
      for (int fc = 0; fc < 4; fc++){
        bf16x8 bb = *(const bf16x8*)&PS(fc * 16 + (lane & 15), kbase);
        accY[fc] = mfma16(cf.v, bb, accY[fc]);
      }
    }
  }
  __syncthreads();
  {
    int lr = w * 16 + ((lane >> 4) << 2);
    #pragma unroll
    for (int fc = 0; fc < 8; fc++){
      int s = fc * 16 + (lane & 15);
      #pragma unroll
      for (int j = 0; j < 4; j++){
        int l = l0 + lr + j;
        float v = (s <= l) ? accS[fc][j] * expf(ac[l] - ac[s]) : 0.f;
        CS(lr + j, s) = f2b(v);
      }
    }
  }
  #pragma unroll
  for (int p = 0; p < 8; p++){
    int lr = p * 16 + (tid >> 4);
    int p4 = (tid & 15) * 4;
    float dtl = dtb[(rowbase + lr) * NH + hh];
    u16x4 v = *(const u16x4*)&xbc[(rowbase + lr) * CONVD + hh * HD + p4];
    BS(p4 + 0, lr) = f2b(b2f(v[0]) * dtl);
    BS(p4 + 1, lr) = f2b(b2f(v[1]) * dtl);
    BS(p4 + 2, lr) = f2b(b2f(v[2]) * dtl);
    BS(p4 + 3, lr) = f2b(b2f(v[3]) * dtl);
  }
  __syncthreads();
  #pragma unroll
  for (int kk = 0; kk < 4; kk++){
    bf16x8 a = *(const bf16x8*)&CS(w * 16 + (lane & 15), kk * 32 + (lane >> 4) * 8);
    #pragma unroll
    for (int fc = 0; fc < 4; fc++){
      bf16x8 bb = *(const bf16x8*)&BS(fc * 16 + (lane & 15), kk * 32 + (lane >> 4) * 8);
      accY[fc] = mfma16(a, bb, accY[fc]);
    }
  }
  float dpar = Dp[hh];
  {
    int lr = w * 16 + ((lane >> 4) << 2);
    #pragma unroll
    for (int fc = 0; fc < 4; fc++){
      int p = fc * 16 + (lane & 15);
      #pragma unroll
      for (int j = 0; j < 4; j++){
        int l = l0 + lr + j;
        float xsv = b2f(xbc[(rowbase + l) * CONVD + hh * HD + p]);
        y[(rowbase + l) * DINNER + hh * HD + p] = f2b(accY[fc][j] + dpar * xsv);
      }
    }
  }
  #undef CS
  #undef BS
  #undef PS
}

extern "C" void kernel_launch(void* const* d_in, const int* in_sizes, int n_in,
                              void* d_out, int out_size, void* d_ws, size_t ws_size,
                              hipStream_t stream)
{
  (void)in_sizes; (void)n_in; (void)out_size; (void)ws_size;
  const float* hidden    = (const float*)d_in[0];
  const float* norm1_w   = (const float*)d_in[1];
  const float* in_proj_w = (const float*)d_in[2];
  const float* conv_w    = (const float*)d_in[3];
  const float* conv_b    = (const float*)d_in[4];
  const float* dt_bias   = (const float*)d_in[5];
  const float* A_log     = (const float*)d_in[6];
  const float* D_param   = (const float*)d_in[7];
  const float* mixer_w   = (const float*)d_in[8];
  const float* out_proj_w= (const float*)d_in[9];
  const float* norm2_w   = (const float*)d_in[10];
  const float* gate_w    = (const float*)d_in[11];
  const float* up_w      = (const float*)d_in[12];
  const float* down_w    = (const float*)d_in[13];

  char* ws = (char*)d_ws;
  unsigned short* zbuf    = (unsigned short*)(ws);                  // bf16 4096x4096 [k2..k10]
  unsigned short* WT_cat  = (unsigned short*)(ws);                  // bf16 11264x2048 interleaved [k12.5..k13]
  unsigned short* WT_down = (unsigned short*)(ws);                  // bf16 2048x5632 [k14..k15]
  unsigned short* xdt     = (unsigned short*)(ws + 33554432ull);    // bf16 4096x4416 [k2..k5]
  unsigned short* states  = (unsigned short*)(ws + 33554432ull);    // bf16 16.7M el  [k7..k9]
  unsigned short* ygn     = (unsigned short*)(ws + 33554432ull);    // bf16 4096x4096 [k10..k11]
  unsigned short* xbc     = (unsigned short*)(ws + 69730304ull);    // bf16 4096x4352 [k5..k9]
  unsigned short* WT_out  = (unsigned short*)(ws + 69730304ull);    // bf16 2048x4096 [k10.5..k11]
  float* dtraw            = (float*)(ws + 105381888ull);            // f32 4096x64 [k2..k3]
  float* dtb              = (float*)(ws + 106430464ull);            // f32 4096x64 [k3..k9]
  float* acum             = (float*)(ws + 107479040ull);            // f32 128x2048 [k4..k9]
  unsigned short* ybb     = (unsigned short*)(ws + 108527616ull);   // bf16 4096x4096 [k6..k10]
  unsigned short* hbuf    = (unsigned short*)(ws + 108527616ull);   // bf16 4096x2048 [k1..k2]
  unsigned short* gbuf    = (unsigned short*)(ws + 108527616ull);   // bf16 4096x5632 [k13..k15]
  unsigned short* WT_in   = (unsigned short*)(ws + 125304832ull);   // bf16 8704x2048 [k0..k2]
  unsigned short* h2      = (unsigned short*)(ws + 154664960ull);   // bf16 4096x2048 [k12..k13]
  float* h1               = (float*)d_out;
  float* outp             = (float*)d_out;

  const int dynLDS3 = 73728;   // 3 x 24KB -> 2 blocks/CU
  const int dynLDS4 = 49152;   // 3 x 16KB -> 3 blocks/CU
  const int dynLDSY = 70144;   // Cs+Bs+Ps+ac -> 2 blocks/CU
  hipFuncSetAttribute((const void*)gemm3_kernel,
                      hipFuncAttributeMaxDynamicSharedMemorySize, dynLDS3);
  hipFuncSetAttribute((const void*)gemm4_kernel,
                      hipFuncAttributeMaxDynamicSharedMemorySize, dynLDS4);
  hipFuncSetAttribute((const void*)ssd_y_kernel,
                      hipFuncAttributeMaxDynamicSharedMemorySize, dynLDSY);

  // 0. convert in_proj weight -> bf16 [8704][2048]
  wconv_kernel<<<dim3(136, 32), 256, 0, stream>>>(in_proj_w, WT_in, DMODEL, INP, 1, 0);
  // 1. h = rmsnorm(hidden) -> bf16
  rms_kernel<<<NTOK, 256, 0, stream>>>(hidden, norm1_w, hbuf, DMODEL);
  // 2. zxbcdt = h @ in_proj (gemm3, R14 config: measured-best)
  gemm3_kernel<<<dim3(34, 32), 512, dynLDS3, stream>>>(hbuf, WT_in, nullptr, nullptr,
                                                       zbuf, xdt, DINNER, 0, dtraw,
                                                       NTOK, INP, DMODEL);
  // 3+4. fused softplus + cumsum
  acum_kernel<<<BATCH * NH * NCH, 64, 0, stream>>>(dtraw, dt_bias, A_log, dtb, acum);
  // 5. conv + silu
  conv_kernel<<<dim3(CONVD / 256, LTOT / 4, BATCH), 256, 0, stream>>>(xdt, conv_w, conv_b, xbc);
  // 6. SSD per-chunk states
  ssd_states_kernel<<<dim3(NH, NCH, BATCH), 256, 0, stream>>>(xbc, dtb, acum, states);
  // 7. inter-chunk scan (in-place -> prev)
  scan_kernel<<<dim3(BATCH * NH, 8), 256, 0, stream>>>(states, acum);
  // 8. FUSED Y: Y_diag + Y_off + D*x -> ybb (bf16, one write)
  ssd_y_kernel<<<dim3(NH, NCH * 2, BATCH), 256, dynLDSY, stream>>>(xbc, states, dtb, acum,
                                                                   D_param, ybb);
  // 9. gated rmsnorm: ygn = rmsnorm(y * silu(z))
  rms_gated_kernel<<<NTOK, 256, 0, stream>>>(ybb, zbuf, mixer_w, ygn);
  // 9.5 convert out_proj weight
  wconv_kernel<<<dim3(32, 64), 256, 0, stream>>>(out_proj_w, WT_out, DINNER, DMODEL, 1, 0);
  // 10. h1 = hidden + ygn @ out_proj (into d_out)
  gemm4_kernel<<<dim3(16, 32), 256, dynLDS4, stream>>>(ygn, WT_out, hidden, h1,
                                                       NTOK, DMODEL, DINNER, 4);
  // 11. h2 = rmsnorm(h1) -> bf16
  rms_kernel<<<NTOK, 256, 0, stream>>>(h1, norm2_w, h2, DMODEL);
  // 11.5 convert gate+up weights, column-interleaved
  wconv_kernel<<<dim3(88, 32), 256, 0, stream>>>(gate_w, WT_cat, DMODEL, INTER_, 2, 0);
  wconv_kernel<<<dim3(88, 32), 256, 0, stream>>>(up_w, WT_cat, DMODEL, INTER_, 2, 1);
  // 12. fused gate+up GEMM with GLU epilogue
  gemm3_kernel<<<dim3(44, 32), 512, dynLDS3, stream>>>(h2, WT_cat, nullptr, nullptr,
                                                       gbuf, nullptr, 0, 1, nullptr,
                                                       NTOK, 2 * INTER_, DMODEL);
  // 13. convert down weight
  wconv_kernel<<<dim3(32, 88), 256, 0, stream>>>(down_w, WT_down, INTER_, DMODEL, 1, 0);
  // 14. out = h1 + (g*u) @ down_w (in place on d_out)
  gemm4_kernel<<<dim3(16, 32), 256, dynLDS4, stream>>>(gbuf, WT_down, h1, outp,
                                                       NTOK, DMODEL, INTER_, 4);
}